// Round 11
// baseline (151.657 us; speedup 1.0000x reference)
//
#include <hip/hip_runtime.h>
#include <stdint.h>

typedef short bf16x8 __attribute__((ext_vector_type(8)));
typedef float f32x4 __attribute__((ext_vector_type(4)));

static __device__ __forceinline__ unsigned short f2bf(float f) {
  union { float f; uint32_t u; } c; c.f = f;
  uint32_t u = c.u;
  uint32_t r = (u + 0x7fffu + ((u >> 16) & 1u)) >> 16;  // RNE
  return (unsigned short)r;
}

extern "C" __device__ float __ocml_exp2_f32(float);
static __device__ __forceinline__ float exp2_(float x) {
#if __has_builtin(__builtin_amdgcn_exp2f)
  return __builtin_amdgcn_exp2f(x);
#else
  return __ocml_exp2_f32(x);
#endif
}

static __device__ __forceinline__ uint32_t cvtpk_bf16(float a, float b) {
  uint32_t r;
  asm("v_cvt_pk_bf16_f32 %0, %1, %2" : "=v"(r) : "v"(a), "v"(b));
  return r;  // low16 = bf16(a), high16 = bf16(b)
}

__device__ __forceinline__ void gload_lds16(const void* g, void* l) {
  __builtin_amdgcn_global_load_lds((const __attribute__((address_space(1))) uint32_t*)g,
                                   (__attribute__((address_space(3))) uint32_t*)l, 16, 0, 0);
}

// ---------------------------------------------------------------------------
// Kernel 1: fp32 -> bf16 conversion of activations (q,k,v) and weights.
// Xb: [3][4096][1024] bf16, Wb: [3][1024][1024] bf16
// ---------------------------------------------------------------------------
__global__ __launch_bounds__(256) void k_convert(
    const float* __restrict__ q, const float* __restrict__ k, const float* __restrict__ v,
    const float* __restrict__ Wq, const float* __restrict__ Wk, const float* __restrict__ Wv,
    unsigned short* __restrict__ Xb, unsigned short* __restrict__ Wb) {
  const int NX4 = 3145728;  // 3*4194304/4
  const int NW4 = 786432;   // 3*1048576/4
  int i = blockIdx.x * 256 + threadIdx.x;
  if (i >= NX4 + NW4) return;
  const float* src; unsigned short* dst; int off4;
  if (i < NX4) {
    int a = i >> 20; off4 = i & 1048575;
    src = (a == 0) ? q : (a == 1) ? k : v;
    dst = Xb + (size_t)a * 4194304;
  } else {
    int j = i - NX4;
    int a = j >> 18; off4 = j & 262143;
    src = (a == 0) ? Wq : (a == 1) ? Wk : Wv;
    dst = Wb + (size_t)a * 1048576;
  }
  float4 f = ((const float4*)src)[off4];
  uint32_t lo = (uint32_t)f2bf(f.x) | ((uint32_t)f2bf(f.y) << 16);
  uint32_t hi = (uint32_t)f2bf(f.z) | ((uint32_t)f2bf(f.w) << 16);
  ((uint2*)dst)[off4] = make_uint2(lo, hi);
}

// ---------------------------------------------------------------------------
// Kernel 2: projection GEMMs  C[m,n] = X[m,:] . W[n,:] + bias[n]  (x W^T + b)
// grid (256, 3): 32x8 tiles of 128x128 per projection g.
// g==0 (Q): scale by 0.125*log2(e)/inv_scale, Qh[b,h,s2,dh]
// g==1 (K): Kh[b,h,s2,dh]
// g==2 (V): VhT[b,h,dh,s2] (transposed for attention PV)
// Epilogue r11: packed 8B stores. For g<2 the MFMA operands are SWAPPED
// (acc = C^T: reg-quad axis = n = dh, contiguous in Qh/Kh rows); for g==2
// original orientation (reg-quad = m = s2, contiguous in VhT rows).
// ---------------------------------------------------------------------------
__global__ __launch_bounds__(256) void k_proj(
    const unsigned short* __restrict__ Xb, const unsigned short* __restrict__ Wb,
    const float* __restrict__ bq, const float* __restrict__ bk, const float* __restrict__ bv,
    const float* __restrict__ inv_scale,
    unsigned short* __restrict__ Qh, unsigned short* __restrict__ Kh,
    unsigned short* __restrict__ VhT) {
  __shared__ __align__(16) unsigned short At[128 * 32];
  __shared__ __align__(16) unsigned short Bt[128 * 32];
  const int g = blockIdx.y;
  const int m0 = (blockIdx.x >> 3) * 128, n0 = (blockIdx.x & 7) * 128;
  const unsigned short* X = Xb + (size_t)g * 4194304;
  const unsigned short* W = Wb + (size_t)g * 1048576;
  const int tid = threadIdx.x;
  const int w = tid >> 6, lane = tid & 63;
  const int wr = w >> 1, wc = w & 1;
  const int lq = lane & 15, lg = lane >> 4;

  f32x4 acc[4][4];
#pragma unroll
  for (int a = 0; a < 4; a++)
#pragma unroll
    for (int b = 0; b < 4; b++) acc[a][b] = (f32x4){0.f, 0.f, 0.f, 0.f};

  const bool swapped = (g != 2);

  for (int kt = 0; kt < 32; ++kt) {
#pragma unroll
    for (int p = 0; p < 2; ++p) {
      int i = (w * 2 + p) * 64 + lane;   // 0..511 chunk id, 4 chunks per row
      int row = i >> 2, c = i & 3;
      gload_lds16(X + (size_t)(m0 + row) * 1024 + kt * 32 + c * 8, (char*)At + i * 16);
      gload_lds16(W + (size_t)(n0 + row) * 1024 + kt * 32 + c * 8, (char*)Bt + i * 16);
    }
    __syncthreads();
    bf16x8 af[4], bfr[4];
#pragma unroll
    for (int mi = 0; mi < 4; mi++)
      af[mi] = *(const bf16x8*)((const char*)At + ((wr * 64 + mi * 16 + lq) * 64 + lg * 16));
#pragma unroll
    for (int ni = 0; ni < 4; ni++)
      bfr[ni] = *(const bf16x8*)((const char*)Bt + ((wc * 64 + ni * 16 + lq) * 64 + lg * 16));
    if (swapped) {
#pragma unroll
      for (int mi = 0; mi < 4; mi++)
#pragma unroll
        for (int ni = 0; ni < 4; ni++)
          acc[mi][ni] = __builtin_amdgcn_mfma_f32_16x16x32_bf16(bfr[ni], af[mi], acc[mi][ni], 0, 0, 0);
    } else {
#pragma unroll
      for (int mi = 0; mi < 4; mi++)
#pragma unroll
        for (int ni = 0; ni < 4; ni++)
          acc[mi][ni] = __builtin_amdgcn_mfma_f32_16x16x32_bf16(af[mi], bfr[ni], acc[mi][ni], 0, 0, 0);
    }
    __syncthreads();
  }

  if (g != 2) {
    // acc = C^T: col(lq) = m-local, reg-quad(lg*4+r) = n-local (dh contiguous)
    const float* bias = (g == 0) ? bq : bk;
    unsigned short* dst = (g == 0) ? Qh : Kh;
    const float scale = (g == 0) ? 0.125f * 1.4426950408889634f / inv_scale[0] : 1.0f;
#pragma unroll
    for (int mi = 0; mi < 4; mi++) {
      int row = m0 + wr * 64 + mi * 16 + lq;      // m = s2 row
      int b = row >> 11, s2 = row & 2047;
#pragma unroll
      for (int ni = 0; ni < 4; ni++) {
        int col0 = n0 + wc * 64 + ni * 16 + lg * 4;  // n quad (4 consecutive dh)
        float4 bb = *(const float4*)&bias[col0];
        int h = col0 >> 6, dh0 = col0 & 63;
        uint32_t w0 = (uint32_t)f2bf((acc[mi][ni][0] + bb.x) * scale) |
                      ((uint32_t)f2bf((acc[mi][ni][1] + bb.y) * scale) << 16);
        uint32_t w1 = (uint32_t)f2bf((acc[mi][ni][2] + bb.z) * scale) |
                      ((uint32_t)f2bf((acc[mi][ni][3] + bb.w) * scale) << 16);
        *(uint2*)(dst + (size_t)(b * 16 + h) * 131072 + (size_t)s2 * 64 + dh0) =
            make_uint2(w0, w1);
      }
    }
  } else {
    // acc = C: col(lq) = n-local (dh), reg-quad = m-local (s2 contiguous)
#pragma unroll
    for (int ni = 0; ni < 4; ni++) {
      int col = n0 + wc * 64 + ni * 16 + lq;
      float bb = bv[col];
      int h = col >> 6, dh = col & 63;
#pragma unroll
      for (int mi = 0; mi < 4; mi++) {
        int row0 = m0 + wr * 64 + mi * 16 + lg * 4;  // m quad (4 consecutive s2)
        int b = row0 >> 11, s2 = row0 & 2047;
        uint32_t w0 = (uint32_t)f2bf(acc[mi][ni][0] + bb) |
                      ((uint32_t)f2bf(acc[mi][ni][1] + bb) << 16);
        uint32_t w1 = (uint32_t)f2bf(acc[mi][ni][2] + bb) |
                      ((uint32_t)f2bf(acc[mi][ni][3] + bb) << 16);
        *(uint2*)(VhT + (size_t)((b * 16 + h) * 64 + dh) * 2048 + s2) =
            make_uint2(w0, w1);
      }
    }
  }
}

// ---------------------------------------------------------------------------
// Kernel 3: flash attention (round-8 structure + counted-vmcnt pipeline).
// 256 thr = 4 waves x 32 q-rows; grid 512, XCD-pinned (4 heads/XCD),
// 2 blocks/CU. K,V TRIPLE-buffered in LDS (global_load_lds + XOR chunk
// swizzle); per iter: s_waitcnt vmcnt(4) -> raw s_barrier -> issue
// stage(t+2) -> compute. Frag reads reused across 2 q-row groups.
// Swapped QK^T, log2-domain online softmax, defer-max THR=8, cvt_pk
// P-packing, P via per-wave swizzled LDS.
// ---------------------------------------------------------------------------
__global__ __launch_bounds__(256, 2) void k_attn(
    const unsigned short* __restrict__ Qh, const unsigned short* __restrict__ Kh,
    const unsigned short* __restrict__ VhT, float* __restrict__ Ot) {
  __shared__ __align__(16) unsigned short Kt[3][64 * 64];   // 24 KB
  __shared__ __align__(16) unsigned short Vt[3][64 * 64];   // 24 KB
  __shared__ __align__(16) unsigned short Pl[4][32][64];    // 16 KB (swizzled)
  const int n = blockIdx.x;
  const int xcd = n & 7, slot = n >> 3;        // dispatch round-robins XCDs
  const int bh = (xcd << 2) | (slot >> 4);     // 4 heads per XCD
  const int qt = slot & 15;                    // 16 q-tiles of 128 rows
  const int tid = threadIdx.x;
  const int w = tid >> 6, lane = tid & 63;
  const int lq = lane & 15, lg = lane >> 4;
  const int qbase = qt * 128 + w * 32;

  // Q fragments: 2 row-groups x 2 k-halves
  bf16x8 qf[2][2];
#pragma unroll
  for (int r = 0; r < 2; r++) {
    const unsigned short* qp = Qh + ((size_t)bh * 2048 + qbase + r * 16 + lq) * 64 + lg * 8;
    qf[r][0] = *(const bf16x8*)(qp);
    qf[r][1] = *(const bf16x8*)(qp + 32);
  }

  f32x4 ofr[4][2];
#pragma unroll
  for (int dt = 0; dt < 4; dt++)
#pragma unroll
    for (int r = 0; r < 2; r++) ofr[dt][r] = (f32x4){0.f, 0.f, 0.f, 0.f};
  float m[2] = {-INFINITY, -INFINITY}, l[2] = {0.f, 0.f};

  const unsigned short* kgbase = Kh + (size_t)bh * 131072;
  const unsigned short* vgbase = VhT + (size_t)bh * 131072;

  // staging: 4 gload_lds16 per thread per tile (2 K + 2 V), XOR chunk swizzle
  auto STAGE = [&](int tile, int buf) {
#pragma unroll
    for (int p = 0; p < 2; ++p) {
      int i = p * 256 + tid;  // 0..511, 8 chunks per 64-elem row
      int row = i >> 3, c = i & 7;
      int cs = c ^ (row & 7);
      gload_lds16(kgbase + (size_t)(tile * 64 + row) * 64 + cs * 8, (char*)Kt[buf] + i * 16);
      gload_lds16(vgbase + (size_t)row * 2048 + tile * 64 + cs * 8, (char*)Vt[buf] + i * 16);
    }
  };

  // prologue: stage tiles 0 and 1
  STAGE(0, 0);
  STAGE(1, 1);

  for (int kv = 0; kv < 32; ++kv) {
    // ---- counted wait: stage(kv) = oldest 4 of <=8 outstanding loads
    if (kv == 31) {
      asm volatile("s_waitcnt vmcnt(0)" ::: "memory");
    } else {
      asm volatile("s_waitcnt vmcnt(4)" ::: "memory");
    }
    __builtin_amdgcn_s_barrier();          // raw barrier: no compiler drain
    __builtin_amdgcn_sched_barrier(0);

    // ---- issue stage(kv+2): overwrites buf last read in iter kv-1 (safe
    // past the barrier above); stays in flight across this whole iteration
    if (kv < 30) STAGE(kv + 2, (kv + 2) % 3);

    const char* ktc = (const char*)Kt[kv % 3];
    const char* vtc = (const char*)Vt[kv % 3];

    // ---- QK^T: S^T = K . Q^T  (K-frag read once, used for both row-groups)
    f32x4 sf[4][2];
#pragma unroll
    for (int t4 = 0; t4 < 4; t4++) {
      int row = t4 * 16 + lq;
      int c0 = lg ^ (row & 7), c1 = (4 + lg) ^ (row & 7);
      bf16x8 ka = *(const bf16x8*)(ktc + row * 128 + c0 * 16);
      bf16x8 kc = *(const bf16x8*)(ktc + row * 128 + c1 * 16);
#pragma unroll
      for (int r = 0; r < 2; r++) {
        f32x4 z = (f32x4){0.f, 0.f, 0.f, 0.f};
        z = __builtin_amdgcn_mfma_f32_16x16x32_bf16(ka, qf[r][0], z, 0, 0, 0);
        z = __builtin_amdgcn_mfma_f32_16x16x32_bf16(kc, qf[r][1], z, 0, 0, 0);
        sf[t4][r] = z;
      }
    }

    // ---- online softmax (log2 domain); lane's q = qbase + r*16 + lq
    float pmax[2];
#pragma unroll
    for (int r = 0; r < 2; r++) {
      float a0 = fmaxf(fmaxf(sf[0][r][0], sf[0][r][1]), fmaxf(sf[0][r][2], sf[0][r][3]));
      float a1 = fmaxf(fmaxf(sf[1][r][0], sf[1][r][1]), fmaxf(sf[1][r][2], sf[1][r][3]));
      float a2 = fmaxf(fmaxf(sf[2][r][0], sf[2][r][1]), fmaxf(sf[2][r][2], sf[2][r][3]));
      float a3 = fmaxf(fmaxf(sf[3][r][0], sf[3][r][1]), fmaxf(sf[3][r][2], sf[3][r][3]));
      float a = fmaxf(fmaxf(a0, a1), fmaxf(a2, a3));
      a = fmaxf(a, __shfl_xor(a, 16));
      a = fmaxf(a, __shfl_xor(a, 32));
      pmax[r] = a;
    }
    // defer-max: rescale only when max grew by > 8 (log2 domain -> P <= 256)
    if (__any((pmax[0] > m[0] + 8.f) || (pmax[1] > m[1] + 8.f))) {
#pragma unroll
      for (int r = 0; r < 2; r++) {
        float mn = fmaxf(m[r], pmax[r]);
        float c = exp2_(m[r] - mn);
        m[r] = mn;
        l[r] *= c;
#pragma unroll
        for (int dt = 0; dt < 4; dt++) ofr[dt][r] *= c;
      }
    }

    // ---- exp2, cvt_pk pack to bf16, write P to per-wave LDS (swizzled)
#pragma unroll
    for (int r = 0; r < 2; r++) {
      float ps = 0.f;
#pragma unroll
      for (int t4 = 0; t4 < 4; t4++) {
        float p0 = exp2_(sf[t4][r][0] - m[r]);
        float p1 = exp2_(sf[t4][r][1] - m[r]);
        float p2 = exp2_(sf[t4][r][2] - m[r]);
        float p3 = exp2_(sf[t4][r][3] - m[r]);
        ps += (p0 + p1) + (p2 + p3);
        uint32_t w0 = cvtpk_bf16(p0, p1);
        uint32_t w1 = cvtpk_bf16(p2, p3);
        uint64_t dw = (uint64_t)w0 | ((uint64_t)w1 << 32);
        int ch = (t4 * 2 + (lg >> 1)) ^ (lq & 7);    // 16B-chunk XOR swizzle
        __builtin_memcpy((char*)&Pl[w][r * 16 + lq][0] + ch * 16 + (lg & 1) * 8, &dw, 8);
      }
      ps += __shfl_xor(ps, 16);
      ps += __shfl_xor(ps, 32);
      l[r] += ps;
    }

    // ---- PV: O^T += Vt . P^T  (V-frag read once, used for both row-groups)
    bf16x8 pf[2][2];
#pragma unroll
    for (int r = 0; r < 2; r++)
#pragma unroll
      for (int c = 0; c < 2; c++) {
        int ch = (c * 4 + lg) ^ (lq & 7);
        __builtin_memcpy(&pf[r][c], (const char*)&Pl[w][r * 16 + lq][0] + ch * 16, 16);
      }
    __builtin_amdgcn_s_setprio(1);
#pragma unroll
    for (int dt = 0; dt < 4; dt++) {
      int row = dt * 16 + lq;
      int c0 = lg ^ (row & 7), c1 = (4 + lg) ^ (row & 7);
      bf16x8 va = *(const bf16x8*)(vtc + row * 128 + c0 * 16);
      bf16x8 vc = *(const bf16x8*)(vtc + row * 128 + c1 * 16);
#pragma unroll
      for (int r = 0; r < 2; r++) {
        ofr[dt][r] = __builtin_amdgcn_mfma_f32_16x16x32_bf16(va, pf[r][0], ofr[dt][r], 0, 0, 0);
        ofr[dt][r] = __builtin_amdgcn_mfma_f32_16x16x32_bf16(vc, pf[r][1], ofr[dt][r], 0, 0, 0);
      }
    }
    __builtin_amdgcn_s_setprio(0);
    // no trailing __syncthreads: next iteration's counted wait + raw barrier
    // provides both the stage-ready guarantee and the buffer-reuse ordering
  }

  // coalesced epilogue: Ot[bh][q][d] = O^T[d][q] / l
  float rl[2] = {1.0f / l[0], 1.0f / l[1]};
#pragma unroll
  for (int dt = 0; dt < 4; dt++)
#pragma unroll
    for (int r = 0; r < 2; r++) {
      f32x4 o = ofr[dt][r] * rl[r];
      size_t q = qbase + r * 16 + lq;
      *(f32x4*)(Ot + ((size_t)bh * 2048 + q) * 64 + dt * 16 + lg * 4) = o;
    }
}

// ---------------------------------------------------------------------------
// Kernel 4: layout transpose  out[b][s2][dh][h] = Ot[b*16+h][s2][dh]
// 1 float4 (4 h-values) per thread: 4 coalesced strided reads + 1 float4 write.
// ---------------------------------------------------------------------------
__global__ __launch_bounds__(256) void k_tr(const float* __restrict__ Ot,
                                            float* __restrict__ out) {
  int u = blockIdx.x * 256 + threadIdx.x;  // 0..1048575
  int h4 = u & 3, dh = (u >> 2) & 63, s2 = (u >> 8) & 2047, b = u >> 19;
  size_t base = ((size_t)(b * 16 + h4 * 4) * 2048 + s2) * 64 + dh;
  float4 o;
  o.x = Ot[base];
  o.y = Ot[base + 131072];
  o.z = Ot[base + 262144];
  o.w = Ot[base + 393216];
  ((float4*)out)[u] = o;
}

// ---------------------------------------------------------------------------
extern "C" void kernel_launch(void* const* d_in, const int* in_sizes, int n_in,
                              void* d_out, int out_size, void* d_ws, size_t ws_size,
                              hipStream_t stream) {
  const float* q   = (const float*)d_in[0];
  const float* k   = (const float*)d_in[1];
  const float* v   = (const float*)d_in[2];
  // d_in[3] = mask (unused by the reference forward)
  const float* inv = (const float*)d_in[4];
  const float* Wq  = (const float*)d_in[5];
  const float* bq  = (const float*)d_in[6];
  const float* Wk  = (const float*)d_in[7];
  const float* bk  = (const float*)d_in[8];
  const float* Wv  = (const float*)d_in[9];
  const float* bv  = (const float*)d_in[10];

  char* ws = (char*)d_ws;
  unsigned short* Xb  = (unsigned short*)(ws);              // 25,165,824 B
  unsigned short* Wb  = (unsigned short*)(ws + 25165824);   //  6,291,456 B
  unsigned short* Qh  = (unsigned short*)(ws + 31457280);   //  8,388,608 B
  unsigned short* Kh  = (unsigned short*)(ws + 39845888);   //  8,388,608 B
  unsigned short* VhT = (unsigned short*)(ws + 48234496);   //  8,388,608 B
  float*          Ot  = (float*)(ws);                       // 16,777,216 B (aliases dead Xb)

  k_convert<<<15360, 256, 0, stream>>>(q, k, v, Wq, Wk, Wv, Xb, Wb);
  k_proj<<<dim3(256, 3), 256, 0, stream>>>(Xb, Wb, bq, bk, bv, inv, Qh, Kh, VhT);
  k_attn<<<512, 256, 0, stream>>>(Qh, Kh, VhT, Ot);
  k_tr<<<4096, 256, 0, stream>>>(Ot, (float*)d_out);
}

// Round 12
// 125.319 us; speedup vs baseline: 1.2102x; 1.2102x over previous
//
#include <hip/hip_runtime.h>
#include <stdint.h>

typedef short bf16x8 __attribute__((ext_vector_type(8)));
typedef float f32x4 __attribute__((ext_vector_type(4)));

static __device__ __forceinline__ unsigned short f2bf(float f) {
  union { float f; uint32_t u; } c; c.f = f;
  uint32_t u = c.u;
  uint32_t r = (u + 0x7fffu + ((u >> 16) & 1u)) >> 16;  // RNE
  return (unsigned short)r;
}

extern "C" __device__ float __ocml_exp2_f32(float);
static __device__ __forceinline__ float exp2_(float x) {
#if __has_builtin(__builtin_amdgcn_exp2f)
  return __builtin_amdgcn_exp2f(x);
#else
  return __ocml_exp2_f32(x);
#endif
}

static __device__ __forceinline__ uint32_t cvtpk_bf16(float a, float b) {
  uint32_t r;
  asm("v_cvt_pk_bf16_f32 %0, %1, %2" : "=v"(r) : "v"(a), "v"(b));
  return r;  // low16 = bf16(a), high16 = bf16(b)
}

__device__ __forceinline__ void gload_lds16(const void* g, void* l) {
  __builtin_amdgcn_global_load_lds((const __attribute__((address_space(1))) uint32_t*)g,
                                   (__attribute__((address_space(3))) uint32_t*)l, 16, 0, 0);
}

// ---------------------------------------------------------------------------
// Kernel 1: fp32 -> bf16 conversion of activations (q,k,v) and weights.
// Xb: [3][4096][1024] bf16, Wb: [3][1024][1024] bf16
// ---------------------------------------------------------------------------
__global__ __launch_bounds__(256) void k_convert(
    const float* __restrict__ q, const float* __restrict__ k, const float* __restrict__ v,
    const float* __restrict__ Wq, const float* __restrict__ Wk, const float* __restrict__ Wv,
    unsigned short* __restrict__ Xb, unsigned short* __restrict__ Wb) {
  const int NX4 = 3145728;  // 3*4194304/4
  const int NW4 = 786432;   // 3*1048576/4
  int i = blockIdx.x * 256 + threadIdx.x;
  if (i >= NX4 + NW4) return;
  const float* src; unsigned short* dst; int off4;
  if (i < NX4) {
    int a = i >> 20; off4 = i & 1048575;
    src = (a == 0) ? q : (a == 1) ? k : v;
    dst = Xb + (size_t)a * 4194304;
  } else {
    int j = i - NX4;
    int a = j >> 18; off4 = j & 262143;
    src = (a == 0) ? Wq : (a == 1) ? Wk : Wv;
    dst = Wb + (size_t)a * 1048576;
  }
  float4 f = ((const float4*)src)[off4];
  uint32_t lo = (uint32_t)f2bf(f.x) | ((uint32_t)f2bf(f.y) << 16);
  uint32_t hi = (uint32_t)f2bf(f.z) | ((uint32_t)f2bf(f.w) << 16);
  ((uint2*)dst)[off4] = make_uint2(lo, hi);
}

// ---------------------------------------------------------------------------
// Kernel 2: projection GEMMs  C[m,n] = X[m,:] . W[n,:] + bias[n]  (x W^T + b)
// grid (256, 3): 32x8 tiles of 128x128 per projection g.
// r12: tile decode m = x&31, n = x>>5 so x%8 == m%8 -> the 8 n-blocks
// sharing an X panel land on ONE XCD (dispatch XCD = linear_id % 8, and
// 256 | grid.x so y doesn't shift it). Per XCD per g: 4 X panels (1MB) +
// 8 W panels (2MB) = 3MB < 4MB L2 -> X re-fetch 8x -> ~1x.
// g==0 (Q): scale by 0.125*log2(e)/inv_scale, Qh[b,h,s2,dh]
// g==1 (K): Kh[b,h,s2,dh];  g==2 (V): VhT[b,h,dh,s2]
// ---------------------------------------------------------------------------
__global__ __launch_bounds__(256) void k_proj(
    const unsigned short* __restrict__ Xb, const unsigned short* __restrict__ Wb,
    const float* __restrict__ bq, const float* __restrict__ bk, const float* __restrict__ bv,
    const float* __restrict__ inv_scale,
    unsigned short* __restrict__ Qh, unsigned short* __restrict__ Kh,
    unsigned short* __restrict__ VhT) {
  __shared__ __align__(16) unsigned short At[128 * 32];
  __shared__ __align__(16) unsigned short Bt[128 * 32];
  const int g = blockIdx.y;
  const int m0 = (blockIdx.x & 31) * 128, n0 = (blockIdx.x >> 5) * 128;
  const unsigned short* X = Xb + (size_t)g * 4194304;
  const unsigned short* W = Wb + (size_t)g * 1048576;
  const int tid = threadIdx.x;
  const int w = tid >> 6, lane = tid & 63;
  const int wr = w >> 1, wc = w & 1;
  const int lq = lane & 15, lg = lane >> 4;

  f32x4 acc[4][4];
#pragma unroll
  for (int a = 0; a < 4; a++)
#pragma unroll
    for (int b = 0; b < 4; b++) acc[a][b] = (f32x4){0.f, 0.f, 0.f, 0.f};

  for (int kt = 0; kt < 32; ++kt) {
#pragma unroll
    for (int p = 0; p < 2; ++p) {
      int i = (w * 2 + p) * 64 + lane;   // 0..511 chunk id, 4 chunks per row
      int row = i >> 2, c = i & 3;
      gload_lds16(X + (size_t)(m0 + row) * 1024 + kt * 32 + c * 8, (char*)At + i * 16);
      gload_lds16(W + (size_t)(n0 + row) * 1024 + kt * 32 + c * 8, (char*)Bt + i * 16);
    }
    __syncthreads();
    bf16x8 af[4], bfr[4];
#pragma unroll
    for (int mi = 0; mi < 4; mi++)
      af[mi] = *(const bf16x8*)((const char*)At + ((wr * 64 + mi * 16 + lq) * 64 + lg * 16));
#pragma unroll
    for (int ni = 0; ni < 4; ni++)
      bfr[ni] = *(const bf16x8*)((const char*)Bt + ((wc * 64 + ni * 16 + lq) * 64 + lg * 16));
#pragma unroll
    for (int mi = 0; mi < 4; mi++)
#pragma unroll
      for (int ni = 0; ni < 4; ni++)
        acc[mi][ni] = __builtin_amdgcn_mfma_f32_16x16x32_bf16(af[mi], bfr[ni], acc[mi][ni], 0, 0, 0);
    __syncthreads();
  }

  const float* bias = (g == 0) ? bq : (g == 1) ? bk : bv;
  const float scale = (g == 0) ? 0.125f * 1.4426950408889634f / inv_scale[0] : 1.0f;
#pragma unroll
  for (int ni = 0; ni < 4; ni++) {
    int col = n0 + wc * 64 + ni * 16 + lq;
    float bb = bias[col];
    int h = col >> 6, dh = col & 63;
#pragma unroll
    for (int mi = 0; mi < 4; mi++) {
#pragma unroll
      for (int r = 0; r < 4; r++) {
        int row = m0 + wr * 64 + mi * 16 + lg * 4 + r;
        int b = row >> 11, s2 = row & 2047;
        unsigned short bv16 = f2bf((acc[mi][ni][r] + bb) * scale);
        if (g == 0)
          Qh[(size_t)(b * 16 + h) * 131072 + (size_t)s2 * 64 + dh] = bv16;
        else if (g == 1)
          Kh[(size_t)(b * 16 + h) * 131072 + (size_t)s2 * 64 + dh] = bv16;
        else
          VhT[(size_t)((b * 16 + h) * 64 + dh) * 2048 + s2] = bv16;
      }
    }
  }
}

// ---------------------------------------------------------------------------
// Kernel 3: flash attention (round-8 structure + counted-vmcnt pipeline).
// 256 thr = 4 waves x 32 q-rows; grid 512, XCD-pinned (4 heads/XCD),
// 2 blocks/CU. K,V TRIPLE-buffered in LDS (global_load_lds + XOR chunk
// swizzle); per iter: s_waitcnt vmcnt(4) -> raw s_barrier -> issue
// stage(t+2) -> compute. Frag reads reused across 2 q-row groups.
// Swapped QK^T, log2-domain online softmax, defer-max THR=8, cvt_pk
// P-packing, P via per-wave swizzled LDS.
// ---------------------------------------------------------------------------
__global__ __launch_bounds__(256, 2) void k_attn(
    const unsigned short* __restrict__ Qh, const unsigned short* __restrict__ Kh,
    const unsigned short* __restrict__ VhT, float* __restrict__ Ot) {
  __shared__ __align__(16) unsigned short Kt[3][64 * 64];   // 24 KB
  __shared__ __align__(16) unsigned short Vt[3][64 * 64];   // 24 KB
  __shared__ __align__(16) unsigned short Pl[4][32][64];    // 16 KB (swizzled)
  const int n = blockIdx.x;
  const int xcd = n & 7, slot = n >> 3;        // dispatch round-robins XCDs
  const int bh = (xcd << 2) | (slot >> 4);     // 4 heads per XCD
  const int qt = slot & 15;                    // 16 q-tiles of 128 rows
  const int tid = threadIdx.x;
  const int w = tid >> 6, lane = tid & 63;
  const int lq = lane & 15, lg = lane >> 4;
  const int qbase = qt * 128 + w * 32;

  // Q fragments: 2 row-groups x 2 k-halves
  bf16x8 qf[2][2];
#pragma unroll
  for (int r = 0; r < 2; r++) {
    const unsigned short* qp = Qh + ((size_t)bh * 2048 + qbase + r * 16 + lq) * 64 + lg * 8;
    qf[r][0] = *(const bf16x8*)(qp);
    qf[r][1] = *(const bf16x8*)(qp + 32);
  }

  f32x4 ofr[4][2];
#pragma unroll
  for (int dt = 0; dt < 4; dt++)
#pragma unroll
    for (int r = 0; r < 2; r++) ofr[dt][r] = (f32x4){0.f, 0.f, 0.f, 0.f};
  float m[2] = {-INFINITY, -INFINITY}, l[2] = {0.f, 0.f};

  const unsigned short* kgbase = Kh + (size_t)bh * 131072;
  const unsigned short* vgbase = VhT + (size_t)bh * 131072;

  // staging: 4 gload_lds16 per thread per tile (2 K + 2 V), XOR chunk swizzle
  auto STAGE = [&](int tile, int buf) {
#pragma unroll
    for (int p = 0; p < 2; ++p) {
      int i = p * 256 + tid;  // 0..511, 8 chunks per 64-elem row
      int row = i >> 3, c = i & 7;
      int cs = c ^ (row & 7);
      gload_lds16(kgbase + (size_t)(tile * 64 + row) * 64 + cs * 8, (char*)Kt[buf] + i * 16);
      gload_lds16(vgbase + (size_t)row * 2048 + tile * 64 + cs * 8, (char*)Vt[buf] + i * 16);
    }
  };

  // prologue: stage tiles 0 and 1
  STAGE(0, 0);
  STAGE(1, 1);

  for (int kv = 0; kv < 32; ++kv) {
    // ---- counted wait: stage(kv) = oldest 4 of <=8 outstanding loads
    if (kv == 31) {
      asm volatile("s_waitcnt vmcnt(0)" ::: "memory");
    } else {
      asm volatile("s_waitcnt vmcnt(4)" ::: "memory");
    }
    __builtin_amdgcn_s_barrier();          // raw barrier: no compiler drain
    __builtin_amdgcn_sched_barrier(0);

    // ---- issue stage(kv+2): overwrites buf last read in iter kv-1 (safe
    // past the barrier above); stays in flight across this whole iteration
    if (kv < 30) STAGE(kv + 2, (kv + 2) % 3);

    const char* ktc = (const char*)Kt[kv % 3];
    const char* vtc = (const char*)Vt[kv % 3];

    // ---- QK^T: S^T = K . Q^T  (K-frag read once, used for both row-groups)
    f32x4 sf[4][2];
#pragma unroll
    for (int t4 = 0; t4 < 4; t4++) {
      int row = t4 * 16 + lq;
      int c0 = lg ^ (row & 7), c1 = (4 + lg) ^ (row & 7);
      bf16x8 ka = *(const bf16x8*)(ktc + row * 128 + c0 * 16);
      bf16x8 kc = *(const bf16x8*)(ktc + row * 128 + c1 * 16);
#pragma unroll
      for (int r = 0; r < 2; r++) {
        f32x4 z = (f32x4){0.f, 0.f, 0.f, 0.f};
        z = __builtin_amdgcn_mfma_f32_16x16x32_bf16(ka, qf[r][0], z, 0, 0, 0);
        z = __builtin_amdgcn_mfma_f32_16x16x32_bf16(kc, qf[r][1], z, 0, 0, 0);
        sf[t4][r] = z;
      }
    }

    // ---- online softmax (log2 domain); lane's q = qbase + r*16 + lq
    float pmax[2];
#pragma unroll
    for (int r = 0; r < 2; r++) {
      float a0 = fmaxf(fmaxf(sf[0][r][0], sf[0][r][1]), fmaxf(sf[0][r][2], sf[0][r][3]));
      float a1 = fmaxf(fmaxf(sf[1][r][0], sf[1][r][1]), fmaxf(sf[1][r][2], sf[1][r][3]));
      float a2 = fmaxf(fmaxf(sf[2][r][0], sf[2][r][1]), fmaxf(sf[2][r][2], sf[2][r][3]));
      float a3 = fmaxf(fmaxf(sf[3][r][0], sf[3][r][1]), fmaxf(sf[3][r][2], sf[3][r][3]));
      float a = fmaxf(fmaxf(a0, a1), fmaxf(a2, a3));
      a = fmaxf(a, __shfl_xor(a, 16));
      a = fmaxf(a, __shfl_xor(a, 32));
      pmax[r] = a;
    }
    // defer-max: rescale only when max grew by > 8 (log2 domain -> P <= 256)
    if (__any((pmax[0] > m[0] + 8.f) || (pmax[1] > m[1] + 8.f))) {
#pragma unroll
      for (int r = 0; r < 2; r++) {
        float mn = fmaxf(m[r], pmax[r]);
        float c = exp2_(m[r] - mn);
        m[r] = mn;
        l[r] *= c;
#pragma unroll
        for (int dt = 0; dt < 4; dt++) ofr[dt][r] *= c;
      }
    }

    // ---- exp2, cvt_pk pack to bf16, write P to per-wave LDS (swizzled)
#pragma unroll
    for (int r = 0; r < 2; r++) {
      float ps = 0.f;
#pragma unroll
      for (int t4 = 0; t4 < 4; t4++) {
        float p0 = exp2_(sf[t4][r][0] - m[r]);
        float p1 = exp2_(sf[t4][r][1] - m[r]);
        float p2 = exp2_(sf[t4][r][2] - m[r]);
        float p3 = exp2_(sf[t4][r][3] - m[r]);
        ps += (p0 + p1) + (p2 + p3);
        uint32_t w0 = cvtpk_bf16(p0, p1);
        uint32_t w1 = cvtpk_bf16(p2, p3);
        uint64_t dw = (uint64_t)w0 | ((uint64_t)w1 << 32);
        int ch = (t4 * 2 + (lg >> 1)) ^ (lq & 7);    // 16B-chunk XOR swizzle
        __builtin_memcpy((char*)&Pl[w][r * 16 + lq][0] + ch * 16 + (lg & 1) * 8, &dw, 8);
      }
      ps += __shfl_xor(ps, 16);
      ps += __shfl_xor(ps, 32);
      l[r] += ps;
    }

    // ---- PV: O^T += Vt . P^T  (V-frag read once, used for both row-groups)
    bf16x8 pf[2][2];
#pragma unroll
    for (int r = 0; r < 2; r++)
#pragma unroll
      for (int c = 0; c < 2; c++) {
        int ch = (c * 4 + lg) ^ (lq & 7);
        __builtin_memcpy(&pf[r][c], (const char*)&Pl[w][r * 16 + lq][0] + ch * 16, 16);
      }
    __builtin_amdgcn_s_setprio(1);
#pragma unroll
    for (int dt = 0; dt < 4; dt++) {
      int row = dt * 16 + lq;
      int c0 = lg ^ (row & 7), c1 = (4 + lg) ^ (row & 7);
      bf16x8 va = *(const bf16x8*)(vtc + row * 128 + c0 * 16);
      bf16x8 vc = *(const bf16x8*)(vtc + row * 128 + c1 * 16);
#pragma unroll
      for (int r = 0; r < 2; r++) {
        ofr[dt][r] = __builtin_amdgcn_mfma_f32_16x16x32_bf16(va, pf[r][0], ofr[dt][r], 0, 0, 0);
        ofr[dt][r] = __builtin_amdgcn_mfma_f32_16x16x32_bf16(vc, pf[r][1], ofr[dt][r], 0, 0, 0);
      }
    }
    __builtin_amdgcn_s_setprio(0);
    // no trailing __syncthreads: next iteration's counted wait + raw barrier
    // provides both the stage-ready guarantee and the buffer-reuse ordering
  }

  // coalesced epilogue: Ot[bh][q][d] = O^T[d][q] / l
  float rl[2] = {1.0f / l[0], 1.0f / l[1]};
#pragma unroll
  for (int dt = 0; dt < 4; dt++)
#pragma unroll
    for (int r = 0; r < 2; r++) {
      f32x4 o = ofr[dt][r] * rl[r];
      size_t q = qbase + r * 16 + lq;
      *(f32x4*)(Ot + ((size_t)bh * 2048 + q) * 64 + dt * 16 + lg * 4) = o;
    }
}

// ---------------------------------------------------------------------------
// Kernel 4: layout transpose  out[b][s2][dh][h] = Ot[b*16+h][s2][dh]
// 1 float4 (4 h-values) per thread: 4 coalesced strided reads + 1 float4 write.
// ---------------------------------------------------------------------------
__global__ __launch_bounds__(256) void k_tr(const float* __restrict__ Ot,
                                            float* __restrict__ out) {
  int u = blockIdx.x * 256 + threadIdx.x;  // 0..1048575
  int h4 = u & 3, dh = (u >> 2) & 63, s2 = (u >> 8) & 2047, b = u >> 19;
  size_t base = ((size_t)(b * 16 + h4 * 4) * 2048 + s2) * 64 + dh;
  float4 o;
  o.x = Ot[base];
  o.y = Ot[base + 131072];
  o.z = Ot[base + 262144];
  o.w = Ot[base + 393216];
  ((float4*)out)[u] = o;
}

// ---------------------------------------------------------------------------
extern "C" void kernel_launch(void* const* d_in, const int* in_sizes, int n_in,
                              void* d_out, int out_size, void* d_ws, size_t ws_size,
                              hipStream_t stream) {
  const float* q   = (const float*)d_in[0];
  const float* k   = (const float*)d_in[1];
  const float* v   = (const float*)d_in[2];
  // d_in[3] = mask (unused by the reference forward)
  const float* inv = (const float*)d_in[4];
  const float* Wq  = (const float*)d_in[5];
  const float* bq  = (const float*)d_in[6];
  const float* Wk  = (const float*)d_in[7];
  const float* bk  = (const float*)d_in[8];
  const float* Wv  = (const float*)d_in[9];
  const float* bv  = (const float*)d_in[10];

  char* ws = (char*)d_ws;
  unsigned short* Xb  = (unsigned short*)(ws);              // 25,165,824 B
  unsigned short* Wb  = (unsigned short*)(ws + 25165824);   //  6,291,456 B
  unsigned short* Qh  = (unsigned short*)(ws + 31457280);   //  8,388,608 B
  unsigned short* Kh  = (unsigned short*)(ws + 39845888);   //  8,388,608 B
  unsigned short* VhT = (unsigned short*)(ws + 48234496);   //  8,388,608 B
  float*          Ot  = (float*)(ws);                       // 16,777,216 B (aliases dead Xb)

  k_convert<<<15360, 256, 0, stream>>>(q, k, v, Wq, Wk, Wv, Xb, Wb);
  k_proj<<<dim3(256, 3), 256, 0, stream>>>(Xb, Wb, bq, bk, bv, inv, Qh, Kh, VhT);
  k_attn<<<512, 256, 0, stream>>>(Qh, Kh, VhT, Ot);
  k_tr<<<4096, 256, 0, stream>>>(Ot, (float*)d_out);
}

// Round 13
// 124.836 us; speedup vs baseline: 1.2149x; 1.0039x over previous
//
#include <hip/hip_runtime.h>
#include <stdint.h>

typedef short bf16x8 __attribute__((ext_vector_type(8)));
typedef float f32x4 __attribute__((ext_vector_type(4)));

static __device__ __forceinline__ unsigned short f2bf(float f) {
  union { float f; uint32_t u; } c; c.f = f;
  uint32_t u = c.u;
  uint32_t r = (u + 0x7fffu + ((u >> 16) & 1u)) >> 16;  // RNE
  return (unsigned short)r;
}

static __device__ __forceinline__ float bf2f(unsigned short s) {
  union { uint32_t u; float f; } c; c.u = ((uint32_t)s) << 16;
  return c.f;
}

extern "C" __device__ float __ocml_exp2_f32(float);
static __device__ __forceinline__ float exp2_(float x) {
#if __has_builtin(__builtin_amdgcn_exp2f)
  return __builtin_amdgcn_exp2f(x);
#else
  return __ocml_exp2_f32(x);
#endif
}

static __device__ __forceinline__ uint32_t cvtpk_bf16(float a, float b) {
  uint32_t r;
  asm("v_cvt_pk_bf16_f32 %0, %1, %2" : "=v"(r) : "v"(a), "v"(b));
  return r;  // low16 = bf16(a), high16 = bf16(b)
}

__device__ __forceinline__ void gload_lds16(const void* g, void* l) {
  __builtin_amdgcn_global_load_lds((const __attribute__((address_space(1))) uint32_t*)g,
                                   (__attribute__((address_space(3))) uint32_t*)l, 16, 0, 0);
}

// ---------------------------------------------------------------------------
// Kernel 1: fp32 -> bf16 conversion of activations (q,k,v) and weights.
// Xb: [3][4096][1024] bf16, Wb: [3][1024][1024] bf16
// ---------------------------------------------------------------------------
__global__ __launch_bounds__(256) void k_convert(
    const float* __restrict__ q, const float* __restrict__ k, const float* __restrict__ v,
    const float* __restrict__ Wq, const float* __restrict__ Wk, const float* __restrict__ Wv,
    unsigned short* __restrict__ Xb, unsigned short* __restrict__ Wb) {
  const int NX4 = 3145728;  // 3*4194304/4
  const int NW4 = 786432;   // 3*1048576/4
  int i = blockIdx.x * 256 + threadIdx.x;
  if (i >= NX4 + NW4) return;
  const float* src; unsigned short* dst; int off4;
  if (i < NX4) {
    int a = i >> 20; off4 = i & 1048575;
    src = (a == 0) ? q : (a == 1) ? k : v;
    dst = Xb + (size_t)a * 4194304;
  } else {
    int j = i - NX4;
    int a = j >> 18; off4 = j & 262143;
    src = (a == 0) ? Wq : (a == 1) ? Wk : Wv;
    dst = Wb + (size_t)a * 1048576;
  }
  float4 f = ((const float4*)src)[off4];
  uint32_t lo = (uint32_t)f2bf(f.x) | ((uint32_t)f2bf(f.y) << 16);
  uint32_t hi = (uint32_t)f2bf(f.z) | ((uint32_t)f2bf(f.w) << 16);
  ((uint2*)dst)[off4] = make_uint2(lo, hi);
}

// ---------------------------------------------------------------------------
// Kernel 2: projection GEMMs  C[m,n] = X[m,:] . W[n,:] + bias[n]  (x W^T + b)
// grid (256, 3): tiles 128x128; decode m = x&31, n = x>>5 (m-major: the 8
// n-blocks sharing an X panel land on one XCD -> L2 reuse, r12-verified).
// r13: counted-vmcnt TRIPLE-buffered staging (r10-proven pattern): per
// K-step s_waitcnt vmcnt(4) -> raw s_barrier -> issue stage(kt+2) ->
// compute; prefetch stays in flight across the barrier (no drain-to-0).
// g==0 (Q): scale by 0.125*log2(e)/inv_scale, Qh[b,h,s2,dh]
// g==1 (K): Kh[b,h,s2,dh];  g==2 (V): VhT[b,h,dh,s2]
// ---------------------------------------------------------------------------
__global__ __launch_bounds__(256) void k_proj(
    const unsigned short* __restrict__ Xb, const unsigned short* __restrict__ Wb,
    const float* __restrict__ bq, const float* __restrict__ bk, const float* __restrict__ bv,
    const float* __restrict__ inv_scale,
    unsigned short* __restrict__ Qh, unsigned short* __restrict__ Kh,
    unsigned short* __restrict__ VhT) {
  __shared__ __align__(16) unsigned short At[3][128 * 32];  // 24 KB
  __shared__ __align__(16) unsigned short Bt[3][128 * 32];  // 24 KB
  const int g = blockIdx.y;
  const int m0 = (blockIdx.x & 31) * 128, n0 = (blockIdx.x >> 5) * 128;
  const unsigned short* X = Xb + (size_t)g * 4194304;
  const unsigned short* W = Wb + (size_t)g * 1048576;
  const int tid = threadIdx.x;
  const int w = tid >> 6, lane = tid & 63;
  const int wr = w >> 1, wc = w & 1;
  const int lq = lane & 15, lg = lane >> 4;

  f32x4 acc[4][4];
#pragma unroll
  for (int a = 0; a < 4; a++)
#pragma unroll
    for (int b = 0; b < 4; b++) acc[a][b] = (f32x4){0.f, 0.f, 0.f, 0.f};

  auto STAGE = [&](int kt, int buf) {
#pragma unroll
    for (int p = 0; p < 2; ++p) {
      int i = (w * 2 + p) * 64 + lane;   // 0..511 chunk id, 4 chunks per row
      int row = i >> 2, c = i & 3;
      gload_lds16(X + (size_t)(m0 + row) * 1024 + kt * 32 + c * 8, (char*)At[buf] + i * 16);
      gload_lds16(W + (size_t)(n0 + row) * 1024 + kt * 32 + c * 8, (char*)Bt[buf] + i * 16);
    }
  };

  STAGE(0, 0);
  STAGE(1, 1);

  for (int kt = 0; kt < 32; ++kt) {
    if (kt == 31) {
      asm volatile("s_waitcnt vmcnt(0)" ::: "memory");
    } else {
      asm volatile("s_waitcnt vmcnt(4)" ::: "memory");
    }
    __builtin_amdgcn_s_barrier();          // raw barrier: no compiler drain
    __builtin_amdgcn_sched_barrier(0);

    if (kt < 30) STAGE(kt + 2, (kt + 2) % 3);

    const char* at = (const char*)At[kt % 3];
    const char* bt = (const char*)Bt[kt % 3];
    bf16x8 af[4], bfr[4];
#pragma unroll
    for (int mi = 0; mi < 4; mi++)
      af[mi] = *(const bf16x8*)(at + ((wr * 64 + mi * 16 + lq) * 64 + lg * 16));
#pragma unroll
    for (int ni = 0; ni < 4; ni++)
      bfr[ni] = *(const bf16x8*)(bt + ((wc * 64 + ni * 16 + lq) * 64 + lg * 16));
#pragma unroll
    for (int mi = 0; mi < 4; mi++)
#pragma unroll
      for (int ni = 0; ni < 4; ni++)
        acc[mi][ni] = __builtin_amdgcn_mfma_f32_16x16x32_bf16(af[mi], bfr[ni], acc[mi][ni], 0, 0, 0);
    // no trailing __syncthreads: next iteration's counted wait + raw barrier
  }

  const float* bias = (g == 0) ? bq : (g == 1) ? bk : bv;
  const float scale = (g == 0) ? 0.125f * 1.4426950408889634f / inv_scale[0] : 1.0f;
#pragma unroll
  for (int ni = 0; ni < 4; ni++) {
    int col = n0 + wc * 64 + ni * 16 + lq;
    float bb = bias[col];
    int h = col >> 6, dh = col & 63;
#pragma unroll
    for (int mi = 0; mi < 4; mi++) {
#pragma unroll
      for (int r = 0; r < 4; r++) {
        int row = m0 + wr * 64 + mi * 16 + lg * 4 + r;
        int b = row >> 11, s2 = row & 2047;
        unsigned short bv16 = f2bf((acc[mi][ni][r] + bb) * scale);
        if (g == 0)
          Qh[(size_t)(b * 16 + h) * 131072 + (size_t)s2 * 64 + dh] = bv16;
        else if (g == 1)
          Kh[(size_t)(b * 16 + h) * 131072 + (size_t)s2 * 64 + dh] = bv16;
        else
          VhT[(size_t)((b * 16 + h) * 64 + dh) * 2048 + s2] = bv16;
      }
    }
  }
}

// ---------------------------------------------------------------------------
// Kernel 3: flash attention (round-10 verified structure).
// 256 thr = 4 waves x 32 q-rows; grid 512, XCD-pinned (4 heads/XCD),
// 2 blocks/CU. K,V TRIPLE-buffered in LDS (global_load_lds + XOR chunk
// swizzle); counted vmcnt(4) + raw barrier pipeline. Frag reads reused
// across 2 q-row groups. Swapped QK^T, log2-domain online softmax,
// defer-max THR=8, cvt_pk P-packing, P via per-wave swizzled LDS.
// r13: epilogue packs O to bf16 Ot (halves Ot traffic).
// ---------------------------------------------------------------------------
__global__ __launch_bounds__(256, 2) void k_attn(
    const unsigned short* __restrict__ Qh, const unsigned short* __restrict__ Kh,
    const unsigned short* __restrict__ VhT, unsigned short* __restrict__ Ot) {
  __shared__ __align__(16) unsigned short Kt[3][64 * 64];   // 24 KB
  __shared__ __align__(16) unsigned short Vt[3][64 * 64];   // 24 KB
  __shared__ __align__(16) unsigned short Pl[4][32][64];    // 16 KB (swizzled)
  const int n = blockIdx.x;
  const int xcd = n & 7, slot = n >> 3;        // dispatch round-robins XCDs
  const int bh = (xcd << 2) | (slot >> 4);     // 4 heads per XCD
  const int qt = slot & 15;                    // 16 q-tiles of 128 rows
  const int tid = threadIdx.x;
  const int w = tid >> 6, lane = tid & 63;
  const int lq = lane & 15, lg = lane >> 4;
  const int qbase = qt * 128 + w * 32;

  // Q fragments: 2 row-groups x 2 k-halves
  bf16x8 qf[2][2];
#pragma unroll
  for (int r = 0; r < 2; r++) {
    const unsigned short* qp = Qh + ((size_t)bh * 2048 + qbase + r * 16 + lq) * 64 + lg * 8;
    qf[r][0] = *(const bf16x8*)(qp);
    qf[r][1] = *(const bf16x8*)(qp + 32);
  }

  f32x4 ofr[4][2];
#pragma unroll
  for (int dt = 0; dt < 4; dt++)
#pragma unroll
    for (int r = 0; r < 2; r++) ofr[dt][r] = (f32x4){0.f, 0.f, 0.f, 0.f};
  float m[2] = {-INFINITY, -INFINITY}, l[2] = {0.f, 0.f};

  const unsigned short* kgbase = Kh + (size_t)bh * 131072;
  const unsigned short* vgbase = VhT + (size_t)bh * 131072;

  // staging: 4 gload_lds16 per thread per tile (2 K + 2 V), XOR chunk swizzle
  auto STAGE = [&](int tile, int buf) {
#pragma unroll
    for (int p = 0; p < 2; ++p) {
      int i = p * 256 + tid;  // 0..511, 8 chunks per 64-elem row
      int row = i >> 3, c = i & 7;
      int cs = c ^ (row & 7);
      gload_lds16(kgbase + (size_t)(tile * 64 + row) * 64 + cs * 8, (char*)Kt[buf] + i * 16);
      gload_lds16(vgbase + (size_t)row * 2048 + tile * 64 + cs * 8, (char*)Vt[buf] + i * 16);
    }
  };

  // prologue: stage tiles 0 and 1
  STAGE(0, 0);
  STAGE(1, 1);

  for (int kv = 0; kv < 32; ++kv) {
    // ---- counted wait: stage(kv) = oldest 4 of <=8 outstanding loads
    if (kv == 31) {
      asm volatile("s_waitcnt vmcnt(0)" ::: "memory");
    } else {
      asm volatile("s_waitcnt vmcnt(4)" ::: "memory");
    }
    __builtin_amdgcn_s_barrier();          // raw barrier: no compiler drain
    __builtin_amdgcn_sched_barrier(0);

    // ---- issue stage(kv+2): overwrites buf last read in iter kv-1 (safe
    // past the barrier above); stays in flight across this whole iteration
    if (kv < 30) STAGE(kv + 2, (kv + 2) % 3);

    const char* ktc = (const char*)Kt[kv % 3];
    const char* vtc = (const char*)Vt[kv % 3];

    // ---- QK^T: S^T = K . Q^T  (K-frag read once, used for both row-groups)
    f32x4 sf[4][2];
#pragma unroll
    for (int t4 = 0; t4 < 4; t4++) {
      int row = t4 * 16 + lq;
      int c0 = lg ^ (row & 7), c1 = (4 + lg) ^ (row & 7);
      bf16x8 ka = *(const bf16x8*)(ktc + row * 128 + c0 * 16);
      bf16x8 kc = *(const bf16x8*)(ktc + row * 128 + c1 * 16);
#pragma unroll
      for (int r = 0; r < 2; r++) {
        f32x4 z = (f32x4){0.f, 0.f, 0.f, 0.f};
        z = __builtin_amdgcn_mfma_f32_16x16x32_bf16(ka, qf[r][0], z, 0, 0, 0);
        z = __builtin_amdgcn_mfma_f32_16x16x32_bf16(kc, qf[r][1], z, 0, 0, 0);
        sf[t4][r] = z;
      }
    }

    // ---- online softmax (log2 domain); lane's q = qbase + r*16 + lq
    float pmax[2];
#pragma unroll
    for (int r = 0; r < 2; r++) {
      float a0 = fmaxf(fmaxf(sf[0][r][0], sf[0][r][1]), fmaxf(sf[0][r][2], sf[0][r][3]));
      float a1 = fmaxf(fmaxf(sf[1][r][0], sf[1][r][1]), fmaxf(sf[1][r][2], sf[1][r][3]));
      float a2 = fmaxf(fmaxf(sf[2][r][0], sf[2][r][1]), fmaxf(sf[2][r][2], sf[2][r][3]));
      float a3 = fmaxf(fmaxf(sf[3][r][0], sf[3][r][1]), fmaxf(sf[3][r][2], sf[3][r][3]));
      float a = fmaxf(fmaxf(a0, a1), fmaxf(a2, a3));
      a = fmaxf(a, __shfl_xor(a, 16));
      a = fmaxf(a, __shfl_xor(a, 32));
      pmax[r] = a;
    }
    // defer-max: rescale only when max grew by > 8 (log2 domain -> P <= 256)
    if (__any((pmax[0] > m[0] + 8.f) || (pmax[1] > m[1] + 8.f))) {
#pragma unroll
      for (int r = 0; r < 2; r++) {
        float mn = fmaxf(m[r], pmax[r]);
        float c = exp2_(m[r] - mn);
        m[r] = mn;
        l[r] *= c;
#pragma unroll
        for (int dt = 0; dt < 4; dt++) ofr[dt][r] *= c;
      }
    }

    // ---- exp2, cvt_pk pack to bf16, write P to per-wave LDS (swizzled)
#pragma unroll
    for (int r = 0; r < 2; r++) {
      float ps = 0.f;
#pragma unroll
      for (int t4 = 0; t4 < 4; t4++) {
        float p0 = exp2_(sf[t4][r][0] - m[r]);
        float p1 = exp2_(sf[t4][r][1] - m[r]);
        float p2 = exp2_(sf[t4][r][2] - m[r]);
        float p3 = exp2_(sf[t4][r][3] - m[r]);
        ps += (p0 + p1) + (p2 + p3);
        uint32_t w0 = cvtpk_bf16(p0, p1);
        uint32_t w1 = cvtpk_bf16(p2, p3);
        uint64_t dw = (uint64_t)w0 | ((uint64_t)w1 << 32);
        int ch = (t4 * 2 + (lg >> 1)) ^ (lq & 7);    // 16B-chunk XOR swizzle
        __builtin_memcpy((char*)&Pl[w][r * 16 + lq][0] + ch * 16 + (lg & 1) * 8, &dw, 8);
      }
      ps += __shfl_xor(ps, 16);
      ps += __shfl_xor(ps, 32);
      l[r] += ps;
    }

    // ---- PV: O^T += Vt . P^T  (V-frag read once, used for both row-groups)
    bf16x8 pf[2][2];
#pragma unroll
    for (int r = 0; r < 2; r++)
#pragma unroll
      for (int c = 0; c < 2; c++) {
        int ch = (c * 4 + lg) ^ (lq & 7);
        __builtin_memcpy(&pf[r][c], (const char*)&Pl[w][r * 16 + lq][0] + ch * 16, 16);
      }
    __builtin_amdgcn_s_setprio(1);
#pragma unroll
    for (int dt = 0; dt < 4; dt++) {
      int row = dt * 16 + lq;
      int c0 = lg ^ (row & 7), c1 = (4 + lg) ^ (row & 7);
      bf16x8 va = *(const bf16x8*)(vtc + row * 128 + c0 * 16);
      bf16x8 vc = *(const bf16x8*)(vtc + row * 128 + c1 * 16);
#pragma unroll
      for (int r = 0; r < 2; r++) {
        ofr[dt][r] = __builtin_amdgcn_mfma_f32_16x16x32_bf16(va, pf[r][0], ofr[dt][r], 0, 0, 0);
        ofr[dt][r] = __builtin_amdgcn_mfma_f32_16x16x32_bf16(vc, pf[r][1], ofr[dt][r], 0, 0, 0);
      }
    }
    __builtin_amdgcn_s_setprio(0);
    // no trailing __syncthreads: next iteration's counted wait + raw barrier
  }

  // coalesced epilogue: Ot[bh][q][d] = bf16(O^T[d][q] / l)
  float rl[2] = {1.0f / l[0], 1.0f / l[1]};
#pragma unroll
  for (int dt = 0; dt < 4; dt++)
#pragma unroll
    for (int r = 0; r < 2; r++) {
      f32x4 o = ofr[dt][r] * rl[r];
      uint2 pk = make_uint2(cvtpk_bf16(o[0], o[1]), cvtpk_bf16(o[2], o[3]));
      size_t q = qbase + r * 16 + lq;
      *(uint2*)(Ot + ((size_t)bh * 2048 + q) * 64 + dt * 16 + lg * 4) = pk;
    }
}

// ---------------------------------------------------------------------------
// Kernel 4: layout transpose  out[b][s2][dh][h] = fp32(Ot[b*16+h][s2][dh])
// 1 float4 (4 h-values) per thread: 4 strided bf16 reads + 1 float4 write.
// ---------------------------------------------------------------------------
__global__ __launch_bounds__(256) void k_tr(const unsigned short* __restrict__ Ot,
                                            float* __restrict__ out) {
  int u = blockIdx.x * 256 + threadIdx.x;  // 0..1048575
  int h4 = u & 3, dh = (u >> 2) & 63, s2 = (u >> 8) & 2047, b = u >> 19;
  size_t base = ((size_t)(b * 16 + h4 * 4) * 2048 + s2) * 64 + dh;
  float4 o;
  o.x = bf2f(Ot[base]);
  o.y = bf2f(Ot[base + 131072]);
  o.z = bf2f(Ot[base + 262144]);
  o.w = bf2f(Ot[base + 393216]);
  ((float4*)out)[u] = o;
}

// ---------------------------------------------------------------------------
extern "C" void kernel_launch(void* const* d_in, const int* in_sizes, int n_in,
                              void* d_out, int out_size, void* d_ws, size_t ws_size,
                              hipStream_t stream) {
  const float* q   = (const float*)d_in[0];
  const float* k   = (const float*)d_in[1];
  const float* v   = (const float*)d_in[2];
  // d_in[3] = mask (unused by the reference forward)
  const float* inv = (const float*)d_in[4];
  const float* Wq  = (const float*)d_in[5];
  const float* bq  = (const float*)d_in[6];
  const float* Wk  = (const float*)d_in[7];
  const float* bk  = (const float*)d_in[8];
  const float* Wv  = (const float*)d_in[9];
  const float* bv  = (const float*)d_in[10];

  char* ws = (char*)d_ws;
  unsigned short* Xb  = (unsigned short*)(ws);              // 25,165,824 B
  unsigned short* Wb  = (unsigned short*)(ws + 25165824);   //  6,291,456 B
  unsigned short* Qh  = (unsigned short*)(ws + 31457280);   //  8,388,608 B
  unsigned short* Kh  = (unsigned short*)(ws + 39845888);   //  8,388,608 B
  unsigned short* VhT = (unsigned short*)(ws + 48234496);   //  8,388,608 B
  unsigned short* Ot  = (unsigned short*)(ws);              //  8,388,608 B (aliases dead Xb)

  k_convert<<<15360, 256, 0, stream>>>(q, k, v, Wq, Wk, Wv, Xb, Wb);
  k_proj<<<dim3(256, 3), 256, 0, stream>>>(Xb, Wb, bq, bk, bv, inv, Qh, Kh, VhT);
  k_attn<<<512, 256, 0, stream>>>(Qh, Kh, VhT, Ot);
  k_tr<<<4096, 256, 0, stream>>>(Ot, (float*)d_out);
}

// Round 16
// 124.165 us; speedup vs baseline: 1.2214x; 1.0054x over previous
//
#include <hip/hip_runtime.h>
#include <stdint.h>

typedef short bf16x8 __attribute__((ext_vector_type(8)));
typedef float f32x4 __attribute__((ext_vector_type(4)));

static __device__ __forceinline__ unsigned short f2bf(float f) {
  union { float f; uint32_t u; } c; c.f = f;
  uint32_t u = c.u;
  uint32_t r = (u + 0x7fffu + ((u >> 16) & 1u)) >> 16;  // RNE
  return (unsigned short)r;
}

static __device__ __forceinline__ float bf2f(unsigned short s) {
  union { uint32_t u; float f; } c; c.u = ((uint32_t)s) << 16;
  return c.f;
}

extern "C" __device__ float __ocml_exp2_f32(float);
static __device__ __forceinline__ float exp2_(float x) {
#if __has_builtin(__builtin_amdgcn_exp2f)
  return __builtin_amdgcn_exp2f(x);
#else
  return __ocml_exp2_f32(x);
#endif
}

static __device__ __forceinline__ uint32_t cvtpk_bf16(float a, float b) {
  uint32_t r;
  asm("v_cvt_pk_bf16_f32 %0, %1, %2" : "=v"(r) : "v"(a), "v"(b));
  return r;  // low16 = bf16(a), high16 = bf16(b)
}

__device__ __forceinline__ void gload_lds16(const void* g, void* l) {
  __builtin_amdgcn_global_load_lds((const __attribute__((address_space(1))) uint32_t*)g,
                                   (__attribute__((address_space(3))) uint32_t*)l, 16, 0, 0);
}

// ---------------------------------------------------------------------------
// Kernel 1: fp32 -> bf16 conversion of activations (q,k,v) and weights.
// Xb: [3][4096][1024] bf16, Wb: [3][1024][1024] bf16
// ---------------------------------------------------------------------------
__global__ __launch_bounds__(256) void k_convert(
    const float* __restrict__ q, const float* __restrict__ k, const float* __restrict__ v,
    const float* __restrict__ Wq, const float* __restrict__ Wk, const float* __restrict__ Wv,
    unsigned short* __restrict__ Xb, unsigned short* __restrict__ Wb) {
  const int NX4 = 3145728;  // 3*4194304/4
  const int NW4 = 786432;   // 3*1048576/4
  int i = blockIdx.x * 256 + threadIdx.x;
  if (i >= NX4 + NW4) return;
  const float* src; unsigned short* dst; int off4;
  if (i < NX4) {
    int a = i >> 20; off4 = i & 1048575;
    src = (a == 0) ? q : (a == 1) ? k : v;
    dst = Xb + (size_t)a * 4194304;
  } else {
    int j = i - NX4;
    int a = j >> 18; off4 = j & 262143;
    src = (a == 0) ? Wq : (a == 1) ? Wk : Wv;
    dst = Wb + (size_t)a * 1048576;
  }
  float4 f = ((const float4*)src)[off4];
  uint32_t lo = (uint32_t)f2bf(f.x) | ((uint32_t)f2bf(f.y) << 16);
  uint32_t hi = (uint32_t)f2bf(f.z) | ((uint32_t)f2bf(f.w) << 16);
  ((uint2*)dst)[off4] = make_uint2(lo, hi);
}

// ---------------------------------------------------------------------------
// Kernel 2: projection GEMMs  C[m,n] = X[m,:] . W[n,:] + bias[n]  (x W^T + b)
// grid (256, 3): tiles 128x128; decode m = x&31, n = x>>5 (m-major: the 8
// n-blocks sharing an X panel land on one XCD -> L2 reuse, r12-verified).
// Counted-vmcnt triple-buffered staging (r13, neutral-verified).
// g==0 (Q): scale by 0.125*log2(e)/inv_scale, Qh[b,h,s2,dh]
// g==1 (K): Kh[b,h,s2,dh];  g==2 (V): VhT[b,h,dh,s2]
// ---------------------------------------------------------------------------
__global__ __launch_bounds__(256) void k_proj(
    const unsigned short* __restrict__ Xb, const unsigned short* __restrict__ Wb,
    const float* __restrict__ bq, const float* __restrict__ bk, const float* __restrict__ bv,
    const float* __restrict__ inv_scale,
    unsigned short* __restrict__ Qh, unsigned short* __restrict__ Kh,
    unsigned short* __restrict__ VhT) {
  __shared__ __align__(16) unsigned short At[3][128 * 32];  // 24 KB
  __shared__ __align__(16) unsigned short Bt[3][128 * 32];  // 24 KB
  const int g = blockIdx.y;
  const int m0 = (blockIdx.x & 31) * 128, n0 = (blockIdx.x >> 5) * 128;
  const unsigned short* X = Xb + (size_t)g * 4194304;
  const unsigned short* W = Wb + (size_t)g * 1048576;
  const int tid = threadIdx.x;
  const int w = tid >> 6, lane = tid & 63;
  const int wr = w >> 1, wc = w & 1;
  const int lq = lane & 15, lg = lane >> 4;

  f32x4 acc[4][4];
#pragma unroll
  for (int a = 0; a < 4; a++)
#pragma unroll
    for (int b = 0; b < 4; b++) acc[a][b] = (f32x4){0.f, 0.f, 0.f, 0.f};

  auto STAGE = [&](int kt, int buf) {
#pragma unroll
    for (int p = 0; p < 2; ++p) {
      int i = (w * 2 + p) * 64 + lane;   // 0..511 chunk id, 4 chunks per row
      int row = i >> 2, c = i & 3;
      gload_lds16(X + (size_t)(m0 + row) * 1024 + kt * 32 + c * 8, (char*)At[buf] + i * 16);
      gload_lds16(W + (size_t)(n0 + row) * 1024 + kt * 32 + c * 8, (char*)Bt[buf] + i * 16);
    }
  };

  STAGE(0, 0);
  STAGE(1, 1);

  for (int kt = 0; kt < 32; ++kt) {
    if (kt == 31) {
      asm volatile("s_waitcnt vmcnt(0)" ::: "memory");
    } else {
      asm volatile("s_waitcnt vmcnt(4)" ::: "memory");
    }
    __builtin_amdgcn_s_barrier();          // raw barrier: no compiler drain
    __builtin_amdgcn_sched_barrier(0);

    if (kt < 30) STAGE(kt + 2, (kt + 2) % 3);

    const char* at = (const char*)At[kt % 3];
    const char* bt = (const char*)Bt[kt % 3];
    bf16x8 af[4], bfr[4];
#pragma unroll
    for (int mi = 0; mi < 4; mi++)
      af[mi] = *(const bf16x8*)(at + ((wr * 64 + mi * 16 + lq) * 64 + lg * 16));
#pragma unroll
    for (int ni = 0; ni < 4; ni++)
      bfr[ni] = *(const bf16x8*)(bt + ((wc * 64 + ni * 16 + lq) * 64 + lg * 16));
#pragma unroll
    for (int mi = 0; mi < 4; mi++)
#pragma unroll
      for (int ni = 0; ni < 4; ni++)
        acc[mi][ni] = __builtin_amdgcn_mfma_f32_16x16x32_bf16(af[mi], bfr[ni], acc[mi][ni], 0, 0, 0);
    // no trailing __syncthreads: next iteration's counted wait + raw barrier
  }

  const float* bias = (g == 0) ? bq : (g == 1) ? bk : bv;
  const float scale = (g == 0) ? 0.125f * 1.4426950408889634f / inv_scale[0] : 1.0f;
#pragma unroll
  for (int ni = 0; ni < 4; ni++) {
    int col = n0 + wc * 64 + ni * 16 + lq;
    float bb = bias[col];
    int h = col >> 6, dh = col & 63;
#pragma unroll
    for (int mi = 0; mi < 4; mi++) {
#pragma unroll
      for (int r = 0; r < 4; r++) {
        int row = m0 + wr * 64 + mi * 16 + lg * 4 + r;
        int b = row >> 11, s2 = row & 2047;
        unsigned short bv16 = f2bf((acc[mi][ni][r] + bb) * scale);
        if (g == 0)
          Qh[(size_t)(b * 16 + h) * 131072 + (size_t)s2 * 64 + dh] = bv16;
        else if (g == 1)
          Kh[(size_t)(b * 16 + h) * 131072 + (size_t)s2 * 64 + dh] = bv16;
        else
          VhT[(size_t)((b * 16 + h) * 64 + dh) * 2048 + s2] = bv16;
      }
    }
  }
}

// ---------------------------------------------------------------------------
// Kernel 3: flash attention (round-10/13 verified structure; r13 verbatim).
// 256 thr = 4 waves x 32 q-rows; grid 512, XCD-pinned (4 heads/XCD),
// 2 blocks/CU. K,V TRIPLE-buffered in LDS (global_load_lds + XOR chunk
// swizzle); counted vmcnt(4) + raw barrier pipeline. Frag reads reused
// across 2 q-row groups. Swapped QK^T, log2-domain online softmax,
// defer-max THR=8, cvt_pk P-packing, P via per-wave swizzled LDS.
// Epilogue packs O to bf16 Ot (halves Ot traffic).
// ---------------------------------------------------------------------------
__global__ __launch_bounds__(256, 2) void k_attn(
    const unsigned short* __restrict__ Qh, const unsigned short* __restrict__ Kh,
    const unsigned short* __restrict__ VhT, unsigned short* __restrict__ Ot) {
  __shared__ __align__(16) unsigned short Kt[3][64 * 64];   // 24 KB
  __shared__ __align__(16) unsigned short Vt[3][64 * 64];   // 24 KB
  __shared__ __align__(16) unsigned short Pl[4][32][64];    // 16 KB (swizzled)
  const int n = blockIdx.x;
  const int xcd = n & 7, slot = n >> 3;        // dispatch round-robins XCDs
  const int bh = (xcd << 2) | (slot >> 4);     // 4 heads per XCD
  const int qt = slot & 15;                    // 16 q-tiles of 128 rows
  const int tid = threadIdx.x;
  const int w = tid >> 6, lane = tid & 63;
  const int lq = lane & 15, lg = lane >> 4;
  const int qbase = qt * 128 + w * 32;

  // Q fragments: 2 row-groups x 2 k-halves
  bf16x8 qf[2][2];
#pragma unroll
  for (int r = 0; r < 2; r++) {
    const unsigned short* qp = Qh + ((size_t)bh * 2048 + qbase + r * 16 + lq) * 64 + lg * 8;
    qf[r][0] = *(const bf16x8*)(qp);
    qf[r][1] = *(const bf16x8*)(qp + 32);
  }

  f32x4 ofr[4][2];
#pragma unroll
  for (int dt = 0; dt < 4; dt++)
#pragma unroll
    for (int r = 0; r < 2; r++) ofr[dt][r] = (f32x4){0.f, 0.f, 0.f, 0.f};
  float m[2] = {-INFINITY, -INFINITY}, l[2] = {0.f, 0.f};

  const unsigned short* kgbase = Kh + (size_t)bh * 131072;
  const unsigned short* vgbase = VhT + (size_t)bh * 131072;

  // staging: 4 gload_lds16 per thread per tile (2 K + 2 V), XOR chunk swizzle
  auto STAGE = [&](int tile, int buf) {
#pragma unroll
    for (int p = 0; p < 2; ++p) {
      int i = p * 256 + tid;  // 0..511, 8 chunks per 64-elem row
      int row = i >> 3, c = i & 7;
      int cs = c ^ (row & 7);
      gload_lds16(kgbase + (size_t)(tile * 64 + row) * 64 + cs * 8, (char*)Kt[buf] + i * 16);
      gload_lds16(vgbase + (size_t)row * 2048 + tile * 64 + cs * 8, (char*)Vt[buf] + i * 16);
    }
  };

  // prologue: stage tiles 0 and 1
  STAGE(0, 0);
  STAGE(1, 1);

  for (int kv = 0; kv < 32; ++kv) {
    // ---- counted wait: stage(kv) = oldest 4 of <=8 outstanding loads
    if (kv == 31) {
      asm volatile("s_waitcnt vmcnt(0)" ::: "memory");
    } else {
      asm volatile("s_waitcnt vmcnt(4)" ::: "memory");
    }
    __builtin_amdgcn_s_barrier();          // raw barrier: no compiler drain
    __builtin_amdgcn_sched_barrier(0);

    // ---- issue stage(kv+2): overwrites buf last read in iter kv-1 (safe
    // past the barrier above); stays in flight across this whole iteration
    if (kv < 30) STAGE(kv + 2, (kv + 2) % 3);

    const char* ktc = (const char*)Kt[kv % 3];
    const char* vtc = (const char*)Vt[kv % 3];

    // ---- QK^T: S^T = K . Q^T  (K-frag read once, used for both row-groups)
    f32x4 sf[4][2];
#pragma unroll
    for (int t4 = 0; t4 < 4; t4++) {
      int row = t4 * 16 + lq;
      int c0 = lg ^ (row & 7), c1 = (4 + lg) ^ (row & 7);
      bf16x8 ka = *(const bf16x8*)(ktc + row * 128 + c0 * 16);
      bf16x8 kc = *(const bf16x8*)(ktc + row * 128 + c1 * 16);
#pragma unroll
      for (int r = 0; r < 2; r++) {
        f32x4 z = (f32x4){0.f, 0.f, 0.f, 0.f};
        z = __builtin_amdgcn_mfma_f32_16x16x32_bf16(ka, qf[r][0], z, 0, 0, 0);
        z = __builtin_amdgcn_mfma_f32_16x16x32_bf16(kc, qf[r][1], z, 0, 0, 0);
        sf[t4][r] = z;
      }
    }

    // ---- online softmax (log2 domain); lane's q = qbase + r*16 + lq
    float pmax[2];
#pragma unroll
    for (int r = 0; r < 2; r++) {
      float a0 = fmaxf(fmaxf(sf[0][r][0], sf[0][r][1]), fmaxf(sf[0][r][2], sf[0][r][3]));
      float a1 = fmaxf(fmaxf(sf[1][r][0], sf[1][r][1]), fmaxf(sf[1][r][2], sf[1][r][3]));
      float a2 = fmaxf(fmaxf(sf[2][r][0], sf[2][r][1]), fmaxf(sf[2][r][2], sf[2][r][3]));
      float a3 = fmaxf(fmaxf(sf[3][r][0], sf[3][r][1]), fmaxf(sf[3][r][2], sf[3][r][3]));
      float a = fmaxf(fmaxf(a0, a1), fmaxf(a2, a3));
      a = fmaxf(a, __shfl_xor(a, 16));
      a = fmaxf(a, __shfl_xor(a, 32));
      pmax[r] = a;
    }
    // defer-max: rescale only when max grew by > 8 (log2 domain -> P <= 256)
    if (__any((pmax[0] > m[0] + 8.f) || (pmax[1] > m[1] + 8.f))) {
#pragma unroll
      for (int r = 0; r < 2; r++) {
        float mn = fmaxf(m[r], pmax[r]);
        float c = exp2_(m[r] - mn);
        m[r] = mn;
        l[r] *= c;
#pragma unroll
        for (int dt = 0; dt < 4; dt++) ofr[dt][r] *= c;
      }
    }

    // ---- exp2, cvt_pk pack to bf16, write P to per-wave LDS (swizzled)
#pragma unroll
    for (int r = 0; r < 2; r++) {
      float ps = 0.f;
#pragma unroll
      for (int t4 = 0; t4 < 4; t4++) {
        float p0 = exp2_(sf[t4][r][0] - m[r]);
        float p1 = exp2_(sf[t4][r][1] - m[r]);
        float p2 = exp2_(sf[t4][r][2] - m[r]);
        float p3 = exp2_(sf[t4][r][3] - m[r]);
        ps += (p0 + p1) + (p2 + p3);
        uint32_t w0 = cvtpk_bf16(p0, p1);
        uint32_t w1 = cvtpk_bf16(p2, p3);
        uint64_t dw = (uint64_t)w0 | ((uint64_t)w1 << 32);
        int ch = (t4 * 2 + (lg >> 1)) ^ (lq & 7);    // 16B-chunk XOR swizzle
        __builtin_memcpy((char*)&Pl[w][r * 16 + lq][0] + ch * 16 + (lg & 1) * 8, &dw, 8);
      }
      ps += __shfl_xor(ps, 16);
      ps += __shfl_xor(ps, 32);
      l[r] += ps;
    }

    // ---- PV: O^T += Vt . P^T  (V-frag read once, used for both row-groups)
    bf16x8 pf[2][2];
#pragma unroll
    for (int r = 0; r < 2; r++)
#pragma unroll
      for (int c = 0; c < 2; c++) {
        int ch = (c * 4 + lg) ^ (lq & 7);
        __builtin_memcpy(&pf[r][c], (const char*)&Pl[w][r * 16 + lq][0] + ch * 16, 16);
      }
    __builtin_amdgcn_s_setprio(1);
#pragma unroll
    for (int dt = 0; dt < 4; dt++) {
      int row = dt * 16 + lq;
      int c0 = lg ^ (row & 7), c1 = (4 + lg) ^ (row & 7);
      bf16x8 va = *(const bf16x8*)(vtc + row * 128 + c0 * 16);
      bf16x8 vc = *(const bf16x8*)(vtc + row * 128 + c1 * 16);
#pragma unroll
      for (int r = 0; r < 2; r++) {
        ofr[dt][r] = __builtin_amdgcn_mfma_f32_16x16x32_bf16(va, pf[r][0], ofr[dt][r], 0, 0, 0);
        ofr[dt][r] = __builtin_amdgcn_mfma_f32_16x16x32_bf16(vc, pf[r][1], ofr[dt][r], 0, 0, 0);
      }
    }
    __builtin_amdgcn_s_setprio(0);
    // no trailing __syncthreads: next iteration's counted wait + raw barrier
  }

  // coalesced epilogue: Ot[bh][q][d] = bf16(O^T[d][q] / l)
  float rl[2] = {1.0f / l[0], 1.0f / l[1]};
#pragma unroll
  for (int dt = 0; dt < 4; dt++)
#pragma unroll
    for (int r = 0; r < 2; r++) {
      f32x4 o = ofr[dt][r] * rl[r];
      uint2 pk = make_uint2(cvtpk_bf16(o[0], o[1]), cvtpk_bf16(o[2], o[3]));
      size_t q = qbase + r * 16 + lq;
      *(uint2*)(Ot + ((size_t)bh * 2048 + q) * 64 + dt * 16 + lg * 4) = pk;
    }
}

// ---------------------------------------------------------------------------
// Kernel 4: layout transpose  out[b][s2][dh][h] = fp32(Ot[b*16+h][s2][dh])
// 1 float4 (4 h-values) per thread: 4 strided bf16 reads + 1 float4 write.
// ---------------------------------------------------------------------------
__global__ __launch_bounds__(256) void k_tr(const unsigned short* __restrict__ Ot,
                                            float* __restrict__ out) {
  int u = blockIdx.x * 256 + threadIdx.x;  // 0..1048575
  int h4 = u & 3, dh = (u >> 2) & 63, s2 = (u >> 8) & 2047, b = u >> 19;
  size_t base = ((size_t)(b * 16 + h4 * 4) * 2048 + s2) * 64 + dh;
  float4 o;
  o.x = bf2f(Ot[base]);
  o.y = bf2f(Ot[base + 131072]);
  o.z = bf2f(Ot[base + 262144]);
  o.w = bf2f(Ot[base + 393216]);
  ((float4*)out)[u] = o;
}

// ---------------------------------------------------------------------------
extern "C" void kernel_launch(void* const* d_in, const int* in_sizes, int n_in,
                              void* d_out, int out_size, void* d_ws, size_t ws_size,
                              hipStream_t stream) {
  const float* q   = (const float*)d_in[0];
  const float* k   = (const float*)d_in[1];
  const float* v   = (const float*)d_in[2];
  // d_in[3] = mask (unused by the reference forward)
  const float* inv = (const float*)d_in[4];
  const float* Wq  = (const float*)d_in[5];
  const float* bq  = (const float*)d_in[6];
  const float* Wk  = (const float*)d_in[7];
  const float* bk  = (const float*)d_in[8];
  const float* Wv  = (const float*)d_in[9];
  const float* bv  = (const float*)d_in[10];

  char* ws = (char*)d_ws;
  unsigned short* Xb  = (unsigned short*)(ws);              // 25,165,824 B
  unsigned short* Wb  = (unsigned short*)(ws + 25165824);   //  6,291,456 B
  unsigned short* Qh  = (unsigned short*)(ws + 31457280);   //  8,388,608 B
  unsigned short* Kh  = (unsigned short*)(ws + 39845888);   //  8,388,608 B
  unsigned short* VhT = (unsigned short*)(ws + 48234496);   //  8,388,608 B
  unsigned short* Ot  = (unsigned short*)(ws);              //  8,388,608 B (aliases dead Xb)

  k_convert<<<15360, 256, 0, stream>>>(q, k, v, Wq, Wk, Wv, Xb, Wb);
  k_proj<<<dim3(256, 3), 256, 0, stream>>>(Xb, Wb, bq, bk, bv, inv, Qh, Kh, VhT);
  k_attn<<<512, 256, 0, stream>>>(Qh, Kh, VhT, Ot);
  k_tr<<<4096, 256, 0, stream>>>(Ot, (float*)d_out);
}